// Round 1
// baseline (695.033 us; speedup 1.0000x reference)
//
#include <hip/hip_runtime.h>
#include <hip/hip_bf16.h>

// Shapes: B=32, T=512, F=32, D=256.  M = B*T = 16384.
#define M_TOT 16384
#define F_N 32
#define D_N 256

typedef float f32x4 __attribute__((ext_vector_type(4)));
typedef short s16x8 __attribute__((ext_vector_type(8)));

__device__ __forceinline__ f32x4 mfma_bf16(s16x8 a, s16x8 b, f32x4 c) {
  // D = A(16x32) * B(32x16) + C ; accumulate in place.
  asm("v_mfma_f32_16x16x32_bf16 %0, %1, %2, %0" : "+v"(c) : "v"(a), "v"(b));
  return c;
}

__device__ __forceinline__ short f2bf(float x) {
  __hip_bfloat16 h = __float2bfloat16(x);
  unsigned short u;
  __builtin_memcpy(&u, &h, 2);
  return (short)u;
}

__device__ __forceinline__ float eluf(float z) {
  return z > 0.f ? z : (__expf(z) - 1.f);
}
__device__ __forceinline__ float sigm(float z) {
  return 1.f / (1.f + __expf(-z));
}

// ---------------------------------------------------------------------------
// Kernel 0: pack f_w2 / f_wp / f_wg (fp32 [32][256][256], d-major) into bf16
// MFMA-B fragment order: PB[mat][f][ks][n16][lane][j] =
//   W[f][ks*32 + (lane>>4)*8 + j][n16*16 + (lane&15)]
// so each main-loop B-fragment load is one coalesced dwordx4 per lane.
// ---------------------------------------------------------------------------
__global__ __launch_bounds__(256) void pack_weights(
    const float* __restrict__ w2, const float* __restrict__ wp,
    const float* __restrict__ wg, s16x8* __restrict__ pbo) {
  int t = blockIdx.x * 256 + threadIdx.x;  // 0 .. 3*32*8*16*64-1 (=786432)
  int l   = t & 63;
  int n16 = (t >> 6) & 15;
  int ks  = (t >> 10) & 7;
  int f   = (t >> 13) & 31;
  int mat = t >> 18;
  const float* src = (mat == 0) ? w2 : ((mat == 1) ? wp : wg);
  int d0 = ks * 32 + ((l >> 4) << 3);
  int e  = n16 * 16 + (l & 15);
  const float* p = src + ((size_t)f * D_N + d0) * D_N + e;
  s16x8 v;
#pragma unroll
  for (int j = 0; j < 8; ++j) v[j] = f2bf(p[(size_t)j * D_N]);
  pbo[t] = v;
}

// ---------------------------------------------------------------------------
// Kernel 1: weight GRN over F=32 + softmax (fp32 exact). One row per thread.
// ---------------------------------------------------------------------------
__global__ __launch_bounds__(256) void vsn_weights(
    const float* __restrict__ x,
    const float* __restrict__ g_w1, const float* __restrict__ g_b1,
    const float* __restrict__ g_w2, const float* __restrict__ g_b2,
    const float* __restrict__ g_wp, const float* __restrict__ g_bp,
    const float* __restrict__ g_wg, const float* __restrict__ g_bg,
    const float* __restrict__ g_gamma, const float* __restrict__ g_beta,
    const float* __restrict__ p_w, const float* __restrict__ p_b,
    float* __restrict__ w_out) {
  __shared__ float xs[256][33];   // +1 pad: kills the 32-way stride conflict
  __shared__ float Wm[5][32][32]; // w1,w2,wp,wg,pw (broadcast reads)
  __shared__ float Bv[7][32];     // b1,b2,bp,bg,gamma,beta,pb
  const int tid = threadIdx.x;
  const long m0 = (long)blockIdx.x * 256;

  for (int i = tid; i < 256 * 32; i += 256) xs[i >> 5][i & 31] = x[m0 * 32 + i];
  for (int i = tid; i < 1024; i += 256) {
    int r = i >> 5, c = i & 31;
    Wm[0][r][c] = g_w1[i];
    Wm[1][r][c] = g_w2[i];
    Wm[2][r][c] = g_wp[i];
    Wm[3][r][c] = g_wg[i];
    Wm[4][r][c] = p_w[i];
  }
  if (tid < 32) {
    Bv[0][tid] = g_b1[tid];
    Bv[1][tid] = g_b2[tid];
    Bv[2][tid] = g_bp[tid];
    Bv[3][tid] = g_bg[tid];
    Bv[4][tid] = g_gamma[tid];
    Bv[5][tid] = g_beta[tid];
    Bv[6][tid] = p_b[tid];
  }
  __syncthreads();

  float h[32], u[32];
  // h = elu(x @ w1 + b1)
#pragma unroll
  for (int i = 0; i < 32; ++i) {
    float s = Bv[0][i];
#pragma unroll
    for (int j = 0; j < 32; ++j) s += xs[tid][j] * Wm[0][j][i];
    h[i] = eluf(s);
  }
  // u = h @ w2 + b2
#pragma unroll
  for (int i = 0; i < 32; ++i) {
    float s = Bv[1][i];
#pragma unroll
    for (int j = 0; j < 32; ++j) s += h[j] * Wm[1][j][i];
    u[i] = s;
  }
  // h = GLU(u) + x   (residual, identity skip)
#pragma unroll
  for (int i = 0; i < 32; ++i) {
    float sp = Bv[2][i], sg = Bv[3][i];
#pragma unroll
    for (int j = 0; j < 32; ++j) {
      sp += u[j] * Wm[2][j][i];
      sg += u[j] * Wm[3][j][i];
    }
    h[i] = sp * sigm(sg) + xs[tid][i];
  }
  // LayerNorm over 32
  float ss = 0.f;
#pragma unroll
  for (int i = 0; i < 32; ++i) ss += h[i];
  float mean = ss * (1.f / 32.f);
  float sq = 0.f;
#pragma unroll
  for (int i = 0; i < 32; ++i) {
    float d = h[i] - mean;
    sq += d * d;
  }
  float rstd = rsqrtf(sq * (1.f / 32.f) + 1e-5f);
#pragma unroll
  for (int i = 0; i < 32; ++i) u[i] = (h[i] - mean) * rstd * Bv[4][i] + Bv[5][i];
  // logits = u @ p_w + p_b
#pragma unroll
  for (int i = 0; i < 32; ++i) {
    float s = Bv[6][i];
#pragma unroll
    for (int j = 0; j < 32; ++j) s += u[j] * Wm[4][j][i];
    h[i] = s;
  }
  // softmax
  float mx = h[0];
#pragma unroll
  for (int i = 1; i < 32; ++i) mx = fmaxf(mx, h[i]);
  float se = 0.f;
#pragma unroll
  for (int i = 0; i < 32; ++i) {
    h[i] = __expf(h[i] - mx);
    se += h[i];
  }
  float inv = 1.f / se;
#pragma unroll
  for (int i = 0; i < 32; ++i) w_out[(m0 + tid) * 32 + i] = h[i] * inv;
}

// ---------------------------------------------------------------------------
// Kernel 2: fused per-feature GRNs + LN + weighted selection.
// 256 blocks x 512 threads. Block = 64 rows; 8 waves as 2(m) x 4(n):
// wave tile = 32 rows x 64 cols; frags are 16x16 (mfma_f32_16x16x32_bf16).
// LDS h1/h2 tiles XOR-swizzled (T2) so ds_read_b128 A-frags are conflict-free.
// ---------------------------------------------------------------------------
__global__ __launch_bounds__(512, 2) void vsn_main(
    const float* __restrict__ x, const float* __restrict__ f_w1,
    const float* __restrict__ f_b1, const float* __restrict__ f_b2,
    const float* __restrict__ f_bp, const float* __restrict__ f_bg,
    const float* __restrict__ f_ws, const float* __restrict__ f_bs,
    const float* __restrict__ f_gamma, const float* __restrict__ f_beta,
    const float* __restrict__ wts, const s16x8* __restrict__ pb,
    float* __restrict__ out) {
  __shared__ __align__(16) short h1s[64 * 256];  // 32 KB, [row][k] bf16 swz
  __shared__ __align__(16) short h2s[64 * 256];  // 32 KB
  __shared__ float xt[64 * 32];                  // x tile
  __shared__ float wt[64 * 32];                  // softmax weights tile
  __shared__ float red[64 * 4 * 2];              // LN partials [row][wn][2]

  const int tid  = threadIdx.x;
  const int lane = tid & 63;
  const int wv   = tid >> 6;  // 0..7
  const int wm   = wv >> 2;   // 0..1 : row half
  const int wn   = wv & 3;    // 0..3 : 64-col strip
  const int l15  = lane & 15;
  const int l4   = lane >> 4;
  const long m0  = (long)blockIdx.x * 64;

  for (int i = tid; i < 64 * 32; i += 512) {
    xt[i] = x[m0 * 32 + i];
    wt[i] = wts[m0 * 32 + i];
  }

  f32x4 acc[2][4];
#pragma unroll
  for (int a = 0; a < 2; ++a)
#pragma unroll
    for (int b = 0; b < 4; ++b) acc[a][b] = (f32x4){0.f, 0.f, 0.f, 0.f};

  __syncthreads();

  for (int f = 0; f < F_N; ++f) {
    // ---- phase 1: h1 = elu(x*w1 + b1) -> LDS bf16 (swizzled) ----
#pragma unroll
    for (int it = 0; it < 4; ++it) {
      int idx = tid + it * 512;  // 0..2047 ; 32 d-blocks of 8 per row
      int row = idx >> 5;
      int db  = idx & 31;
      float xm = xt[row * 32 + f];
      const float* w1p = f_w1 + f * 256 + db * 8;
      const float* b1p = f_b1 + f * 256 + db * 8;
      s16x8 v;
#pragma unroll
      for (int j = 0; j < 8; ++j) v[j] = f2bf(eluf(xm * w1p[j] + b1p[j]));
      *(s16x8*)((char*)h1s + row * 512 + ((db * 16) ^ ((row & 7) << 4))) = v;
    }
    __syncthreads();

    // ---- phase 2: h2 = h1 @ W2 + b2 ----
    f32x4 a2[2][4];
#pragma unroll
    for (int a = 0; a < 2; ++a)
#pragma unroll
      for (int b = 0; b < 4; ++b) a2[a][b] = (f32x4){0.f, 0.f, 0.f, 0.f};
    const s16x8* pb2 = pb + (size_t)f * 8192;
#pragma unroll 2
    for (int ks = 0; ks < 8; ++ks) {
      s16x8 afr[2];
#pragma unroll
      for (int mf = 0; mf < 2; ++mf) {
        int row = wm * 32 + mf * 16 + l15;
        int kb  = ks * 64 + l4 * 16;
        afr[mf] = *(const s16x8*)((char*)h1s + row * 512 + (kb ^ ((row & 7) << 4)));
      }
#pragma unroll
      for (int nf = 0; nf < 4; ++nf) {
        s16x8 bfr = pb2[(ks * 16 + wn * 4 + nf) * 64 + lane];
#pragma unroll
        for (int mf = 0; mf < 2; ++mf) a2[mf][nf] = mfma_bf16(afr[mf], bfr, a2[mf][nf]);
      }
    }
    // epilogue: +b2, cast bf16, store to h2s (swizzled)
#pragma unroll
    for (int nf = 0; nf < 4; ++nf) {
      int col = wn * 64 + nf * 16 + l15;
      float b2v = f_b2[f * 256 + col];
#pragma unroll
      for (int mf = 0; mf < 2; ++mf) {
        int row0 = wm * 32 + mf * 16 + l4 * 4;
#pragma unroll
        for (int r = 0; r < 4; ++r) {
          int row = row0 + r;
          *(short*)((char*)h2s + row * 512 + ((col * 2) ^ ((row & 7) << 4))) =
              f2bf(a2[mf][nf][r] + b2v);
        }
      }
    }
    __syncthreads();

    // ---- phase 3: p = h2 @ Wp, g = h2 @ Wg (shared A-frags) ----
    f32x4 ap[2][4], ag[2][4];
#pragma unroll
    for (int a = 0; a < 2; ++a)
#pragma unroll
      for (int b = 0; b < 4; ++b) {
        ap[a][b] = (f32x4){0.f, 0.f, 0.f, 0.f};
        ag[a][b] = (f32x4){0.f, 0.f, 0.f, 0.f};
      }
    const s16x8* pbp = pb + (size_t)(32 + f) * 8192;
    const s16x8* pbg = pb + (size_t)(64 + f) * 8192;
#pragma unroll 2
    for (int ks = 0; ks < 8; ++ks) {
      s16x8 afr[2];
#pragma unroll
      for (int mf = 0; mf < 2; ++mf) {
        int row = wm * 32 + mf * 16 + l15;
        int kb  = ks * 64 + l4 * 16;
        afr[mf] = *(const s16x8*)((char*)h2s + row * 512 + (kb ^ ((row & 7) << 4)));
      }
#pragma unroll
      for (int nf = 0; nf < 4; ++nf) {
        s16x8 bp_ = pbp[(ks * 16 + wn * 4 + nf) * 64 + lane];
        s16x8 bg_ = pbg[(ks * 16 + wn * 4 + nf) * 64 + lane];
#pragma unroll
        for (int mf = 0; mf < 2; ++mf) {
          ap[mf][nf] = mfma_bf16(afr[mf], bp_, ap[mf][nf]);
          ag[mf][nf] = mfma_bf16(afr[mf], bg_, ag[mf][nf]);
        }
      }
    }

    // ---- phase 4: GLU + residual + LayerNorm + weighted accumulate ----
    float gam[4], bet[4], bpv[4], bgv[4], wsv[4], bsv[4];
#pragma unroll
    for (int nf = 0; nf < 4; ++nf) {
      int col = wn * 64 + nf * 16 + l15;
      bpv[nf] = f_bp[f * 256 + col];
      bgv[nf] = f_bg[f * 256 + col];
      gam[nf] = f_gamma[f * 256 + col];
      bet[nf] = f_beta[f * 256 + col];
      wsv[nf] = f_ws[f * 256 + col];
      bsv[nf] = f_bs[f * 256 + col];
    }
    float vv[2][4][4];
    float s1[2][4], s2[2][4];
#pragma unroll
    for (int mf = 0; mf < 2; ++mf) {
#pragma unroll
      for (int r = 0; r < 4; ++r) {
        int row = wm * 32 + mf * 16 + l4 * 4 + r;
        float xm = xt[row * 32 + f];
        float ss = 0.f, sq = 0.f;
#pragma unroll
        for (int nf = 0; nf < 4; ++nf) {
          float pvv = ap[mf][nf][r] + bpv[nf];
          float gv  = ag[mf][nf][r] + bgv[nf];
          float val = pvv * sigm(gv) + (xm * wsv[nf] + bsv[nf]);
          vv[mf][nf][r] = val;
          ss += val;
          sq += val * val;
        }
        s1[mf][r] = ss;
        s2[mf][r] = sq;
      }
    }
    // reduce across the 16 col-lanes of each 16-lane group
#pragma unroll
    for (int mf = 0; mf < 2; ++mf)
#pragma unroll
      for (int r = 0; r < 4; ++r) {
#pragma unroll
        for (int m = 1; m <= 8; m <<= 1) {
          s1[mf][r] += __shfl_xor(s1[mf][r], m);
          s2[mf][r] += __shfl_xor(s2[mf][r], m);
        }
      }
    if (l15 == 0) {
#pragma unroll
      for (int mf = 0; mf < 2; ++mf)
#pragma unroll
        for (int r = 0; r < 4; ++r) {
          int row = wm * 32 + mf * 16 + l4 * 4 + r;
          red[(row * 4 + wn) * 2]     = s1[mf][r];
          red[(row * 4 + wn) * 2 + 1] = s2[mf][r];
        }
    }
    __syncthreads();
#pragma unroll
    for (int mf = 0; mf < 2; ++mf) {
#pragma unroll
      for (int r = 0; r < 4; ++r) {
        int row = wm * 32 + mf * 16 + l4 * 4 + r;
        float ss = 0.f, sq = 0.f;
#pragma unroll
        for (int w = 0; w < 4; ++w) {
          ss += red[(row * 4 + w) * 2];
          sq += red[(row * 4 + w) * 2 + 1];
        }
        float mean = ss * (1.f / 256.f);
        float var  = sq * (1.f / 256.f) - mean * mean;
        float rstd = rsqrtf(var + 1e-5f);
        float wrow = wt[row * 32 + f];
#pragma unroll
        for (int nf = 0; nf < 4; ++nf) {
          float st = (vv[mf][nf][r] - mean) * rstd * gam[nf] + bet[nf];
          acc[mf][nf][r] += wrow * st;
        }
      }
    }
    __syncthreads();  // protect h1s/h2s/red reuse next feature
  }

  // ---- store selected ----
#pragma unroll
  for (int mf = 0; mf < 2; ++mf)
#pragma unroll
    for (int r = 0; r < 4; ++r) {
      long row = m0 + wm * 32 + mf * 16 + l4 * 4 + r;
#pragma unroll
      for (int nf = 0; nf < 4; ++nf)
        out[row * 256 + wn * 64 + nf * 16 + l15] = acc[mf][nf][r];
    }
}

// ---------------------------------------------------------------------------
extern "C" void kernel_launch(void* const* d_in, const int* in_sizes, int n_in,
                              void* d_out, int out_size, void* d_ws, size_t ws_size,
                              hipStream_t stream) {
  const float* x       = (const float*)d_in[0];
  const float* f_w1    = (const float*)d_in[1];
  const float* f_b1    = (const float*)d_in[2];
  const float* f_w2    = (const float*)d_in[3];
  const float* f_b2    = (const float*)d_in[4];
  const float* f_wp    = (const float*)d_in[5];
  const float* f_bp    = (const float*)d_in[6];
  const float* f_wg    = (const float*)d_in[7];
  const float* f_bg    = (const float*)d_in[8];
  const float* f_ws    = (const float*)d_in[9];
  const float* f_bs    = (const float*)d_in[10];
  const float* f_gamma = (const float*)d_in[11];
  const float* f_beta  = (const float*)d_in[12];
  const float* g_w1    = (const float*)d_in[13];
  const float* g_b1    = (const float*)d_in[14];
  const float* g_w2    = (const float*)d_in[15];
  const float* g_b2    = (const float*)d_in[16];
  const float* g_wp    = (const float*)d_in[17];
  const float* g_bp    = (const float*)d_in[18];
  const float* g_wg    = (const float*)d_in[19];
  const float* g_bg    = (const float*)d_in[20];
  const float* g_gamma = (const float*)d_in[21];
  const float* g_beta  = (const float*)d_in[22];
  const float* p_w     = (const float*)d_in[23];
  const float* p_b     = (const float*)d_in[24];

  float* out_sel = (float*)d_out;                       // [16384, 256]
  float* out_w   = out_sel + (size_t)M_TOT * D_N;       // [16384, 32]
  s16x8* pbw     = (s16x8*)d_ws;                        // 12.6 MB packed bf16

  pack_weights<<<3072, 256, 0, stream>>>(f_w2, f_wp, f_wg, pbw);
  vsn_weights<<<64, 256, 0, stream>>>(x, g_w1, g_b1, g_w2, g_b2, g_wp, g_bp,
                                      g_wg, g_bg, g_gamma, g_beta, p_w, p_b,
                                      out_w);
  vsn_main<<<256, 512, 0, stream>>>(x, f_w1, f_b1, f_b2, f_bp, f_bg, f_ws,
                                    f_bs, f_gamma, f_beta, out_w,
                                    (const s16x8*)d_ws, out_sel);
}